// Round 12
// baseline (806.952 us; speedup 1.0000x reference)
//
#include <hip/hip_runtime.h>

#define TSTEPS 512
#define BATCH  64
#define DIN    256
#define DLAT   512

typedef _Float16 half8_t __attribute__((ext_vector_type(8)));
typedef float    f32x4  __attribute__((ext_vector_type(4)));

// d_ws layout: [0, 512K) = Wm (scan W_h frags); [512K, 768K) = Wf (W_in frags)
#define WS_WF_OFF  (512u * 1024u)
#define WS_TIER2   (512u * 1024u)
#define WS_TIER1   (768u * 1024u)

// ---------------- Kernel A (tier2 fallback): fp32 tiled GEMM --------------------
#define BM 64
#define BN 64
#define BK 32

__global__ __launch_bounds__(256)
void precompute_gemm(const float* __restrict__ x,
                     const float* __restrict__ Win,
                     const float* __restrict__ bh,
                     float* __restrict__ P)
{
    __shared__ float As[BM][BK + 1];
    __shared__ float Ws[BN][BK + 1];
    const int m0  = blockIdx.y * BM;
    const int n0  = blockIdx.x * BN;
    const int tid = threadIdx.x;
    const int tx  = tid & 15;
    const int ty  = tid >> 4;
    const int lr  = tid >> 2;
    const int lc  = (tid & 3) * 8;

    float acc[4][4] = {};

    for (int kk = 0; kk < DIN; kk += BK) {
        const float* ax = x   + (size_t)(m0 + lr) * DIN + kk + lc;
        const float* aw = Win + (size_t)(n0 + lr) * DIN + kk + lc;
        float4 a0 = *(const float4*)(ax);
        float4 a1 = *(const float4*)(ax + 4);
        float4 w0 = *(const float4*)(aw);
        float4 w1 = *(const float4*)(aw + 4);
        As[lr][lc+0]=a0.x; As[lr][lc+1]=a0.y; As[lr][lc+2]=a0.z; As[lr][lc+3]=a0.w;
        As[lr][lc+4]=a1.x; As[lr][lc+5]=a1.y; As[lr][lc+6]=a1.z; As[lr][lc+7]=a1.w;
        Ws[lr][lc+0]=w0.x; Ws[lr][lc+1]=w0.y; Ws[lr][lc+2]=w0.z; Ws[lr][lc+3]=w0.w;
        Ws[lr][lc+4]=w1.x; Ws[lr][lc+5]=w1.y; Ws[lr][lc+6]=w1.z; Ws[lr][lc+7]=w1.w;
        __syncthreads();
        #pragma unroll
        for (int k = 0; k < BK; ++k) {
            float a[4], w[4];
            #pragma unroll
            for (int i = 0; i < 4; ++i) a[i] = As[ty*4+i][k];
            #pragma unroll
            for (int j = 0; j < 4; ++j) w[j] = Ws[tx*4+j][k];
            #pragma unroll
            for (int i = 0; i < 4; ++i)
                #pragma unroll
                for (int j = 0; j < 4; ++j)
                    acc[i][j] += a[i] * w[j];
        }
        __syncthreads();
    }

    float4 bv = *(const float4*)(bh + n0 + tx*4);
    #pragma unroll
    for (int i = 0; i < 4; ++i) {
        float4 v;
        v.x = acc[i][0] + bv.x; v.y = acc[i][1] + bv.y;
        v.z = acc[i][2] + bv.z; v.w = acc[i][3] + bv.w;
        *(float4*)(P + (size_t)(m0 + ty*4 + i) * DLAT + n0 + tx*4) = v;
    }
}

// -------- Pack W_h into MFMA B-fragment order (fp16) ----------------------------
// Tile (kt, ntg): 32 k x 16 n; element (lane, e) = W_h[ntg*16+(lane&15)]
// [kt*32+(lane>>4)*8+e]. Flat: Wm[(tile*64+lane)*8+e], tile = kt*32+ntg.
// Verified on HW R8-R11 (absmax 0.03125).
__global__ __launch_bounds__(256)
void pack_wh_mfma(const float* __restrict__ Wh, _Float16* __restrict__ Wm)
{
    const int idx  = blockIdx.x * 256 + threadIdx.x;  // 32768 = 512 tiles x 64
    const int lane = idx & 63;
    const int tile = idx >> 6;
    const int kt   = tile >> 5;
    const int ntg  = tile & 31;
    const int n    = ntg * 16 + (lane & 15);
    const int k0   = kt * 32 + (lane >> 4) * 8;
    half8_t v;
    #pragma unroll
    for (int e = 0; e < 8; ++e)
        v[e] = (_Float16)Wh[(size_t)n * DLAT + k0 + e];
    *(half8_t*)(Wm + (size_t)idx * 8) = v;
}

// -------- Pack W_in into MFMA B-fragment order (fp16), K = DIN = 256 ------------
__global__ __launch_bounds__(256)
void pack_win_f16(const float* __restrict__ Win, _Float16* __restrict__ Wf)
{
    const int idx  = blockIdx.x * 256 + threadIdx.x;  // 16384 = 256 tiles x 64
    const int lane = idx & 63;
    const int tile = idx >> 6;
    const int kt   = tile >> 5;
    const int ntg  = tile & 31;
    const int n    = ntg * 16 + (lane & 15);
    const int k0   = kt * 32 + (lane >> 4) * 8;
    half8_t v;
    #pragma unroll
    for (int e = 0; e < 8; ++e)
        v[e] = (_Float16)Win[(size_t)n * DIN + k0 + e];
    *(half8_t*)(Wf + (size_t)idx * 8) = v;
}

// ---------------- Kernel A (tier1): f16 MFMA GEMM  P = x @ Win^T + bh -----------
__global__ __launch_bounds__(256)
void precompute_mfma(const float* __restrict__ x,
                     const half8_t* __restrict__ Wf,
                     const float* __restrict__ bh,
                     float* __restrict__ P)
{
    const int tid  = threadIdx.x;
    const int wave = tid >> 6, lane = tid & 63;
    const int wm   = wave >> 1, wn = wave & 1;
    const int m0   = (blockIdx.x >> 2) * 128 + wm * 64;
    const int n0   = (blockIdx.x & 3) * 128 + wn * 64;
    const int col  = lane & 15, rg = lane >> 4;

    float bv[4];
    #pragma unroll
    for (int nt = 0; nt < 4; ++nt) bv[nt] = bh[n0 + nt * 16 + col];

    f32x4 C[4][4] = {};

    #pragma unroll
    for (int kt = 0; kt < 8; ++kt) {
        half8_t A[4];
        #pragma unroll
        for (int mt = 0; mt < 4; ++mt) {
            const float* xp = x + (size_t)(m0 + mt * 16 + col) * DIN
                                + kt * 32 + rg * 8;
            float4 a = *(const float4*)xp;
            float4 b = *(const float4*)(xp + 4);
            half8_t v;
            v[0] = (_Float16)a.x; v[1] = (_Float16)a.y;
            v[2] = (_Float16)a.z; v[3] = (_Float16)a.w;
            v[4] = (_Float16)b.x; v[5] = (_Float16)b.y;
            v[6] = (_Float16)b.z; v[7] = (_Float16)b.w;
            A[mt] = v;
        }
        half8_t B[4];
        #pragma unroll
        for (int nt = 0; nt < 4; ++nt)
            B[nt] = Wf[(size_t)((kt * 32 + (n0 >> 4) + nt) * 64) + lane];
        #pragma unroll
        for (int mt = 0; mt < 4; ++mt)
            #pragma unroll
            for (int nt = 0; nt < 4; ++nt)
                C[mt][nt] = __builtin_amdgcn_mfma_f32_16x16x32_f16(
                                A[mt], B[nt], C[mt][nt], 0, 0, 0);
    }

    #pragma unroll
    for (int mt = 0; mt < 4; ++mt)
        #pragma unroll
        for (int nt = 0; nt < 4; ++nt) {
            #pragma unroll
            for (int r = 0; r < 4; ++r) {
                const int m = m0 + mt * 16 + rg * 4 + r;
                P[(size_t)m * DLAT + n0 + nt * 16 + col] = C[mt][nt][r] + bv[nt];
            }
        }
}

// ---------------- Kernel B: MFMA scan, producer-consumer flags (no barrier) -----
// One chain per WG; 512 threads = 8 waves, 2/SIMD. Wave w owns n [64w,64w+64):
// 4 nt x 16 kt = 64 MFMA/step. Wave p's output feeds exactly kt-tiles {2p,2p+1},
// so the per-step s_barrier is replaced by per-producer LDS flags:
//   flags[p] = steps completed by wave p (release-store after epilogue).
// Consumers walk kt-pairs in rotated order starting at ring-successor (w+1)&7,
// ending on their own always-ready pair; each pair gated by an acquire-poll
// with one-segment lookahead (flag load issued before the previous pair's 8
// MFMAs -> latency hidden). Rotation permutes only init-time LOAD ADDRESSES;
// register indices stay compile-time (no scratch). hbuf double-buffer safety:
// before a wave's step-t epilogue it has observed all 8 flags >= t, so every
// wave finished reading h(t-1) -> safe to overwrite. Deterministic order.
__global__ __launch_bounds__(512, 2)
void rnn_scan_mfma_pc(const half8_t* __restrict__ Wm,   // fragment-packed
                      const float* __restrict__ h0,
                      float* __restrict__ out)          // P in, h_seq out
{
    __shared__ half8_t  ldsB[8 * 14 * 64];   // 112 KB: [(w*14 + slot)*64 + lane]
    __shared__ _Float16 hbuf[2][DLAT];       // 2 KB, double-buffered h
    __shared__ int      flags[8];            // steps completed per wave

    const int b    = blockIdx.x;
    const int tid  = threadIdx.x;
    const int w    = tid >> 6;               // wave 0..7
    const int lane = tid & 63;

    // ---- one-time: B frags in rotated order; j = s*8+q*4+nt static ----
    half8_t bfr[50];
    #pragma unroll
    for (int s = 0; s < 8; ++s) {
        const int ktp = (w + 1 + s) & 7;     // producer for segment s
        #pragma unroll
        for (int q = 0; q < 2; ++q)
            #pragma unroll
            for (int nt = 0; nt < 4; ++nt) {
                const int j = s * 8 + q * 4 + nt;
                half8_t v = Wm[(size_t)(((2 * ktp + q) * 32 + w * 4 + nt) * 64)
                               + lane];
                if (j < 50) bfr[j] = v;
                else        ldsB[(w * 14 + (j - 50)) * 64 + lane] = v;
            }
    }

    hbuf[0][tid] = (_Float16)h0[(size_t)b * DLAT + tid];   // pre-relu h0
    if (tid < 8) flags[tid] = 0;
    __syncthreads();                          // the only barrier

    for (int t = 0; t < TSTEPS; ++t) {
        const int cur = t & 1, nxt = cur ^ 1;
        float* orow = out + ((size_t)t * BATCH + b) * DLAT;
        float pv = orow[w * 64 + lane];       // prefetch P (hidden under MFMAs)

        f32x4 C[4] = {};
        int fcur = __hip_atomic_load(&flags[(w + 1) & 7], __ATOMIC_ACQUIRE,
                                     __HIP_MEMORY_SCOPE_WORKGROUP);
        #pragma unroll
        for (int s = 0; s < 8; ++s) {
            const int ktp = (w + 1 + s) & 7;
            while (fcur < t) {                // steady state: exits immediately
                __builtin_amdgcn_s_sleep(1);
                fcur = __hip_atomic_load(&flags[ktp], __ATOMIC_ACQUIRE,
                                         __HIP_MEMORY_SCOPE_WORKGROUP);
            }
            __builtin_amdgcn_sched_barrier(0);   // no hoisting reads above gate
            int fnext = 0;
            if (s < 7)                        // lookahead: hidden under 8 MFMAs
                fnext = __hip_atomic_load(&flags[(w + 2 + s) & 7],
                                          __ATOMIC_ACQUIRE,
                                          __HIP_MEMORY_SCOPE_WORKGROUP);
            #pragma unroll
            for (int q = 0; q < 2; ++q) {
                const int kt = 2 * ktp + q;
                // broadcast A: 16-lane groups read the same 16B h chunk
                half8_t A = *(const half8_t*)&hbuf[cur][kt * 32 + (lane >> 4) * 8];
                #pragma unroll
                for (int nt = 0; nt < 4; ++nt) {
                    const int j = s * 8 + q * 4 + nt;
                    half8_t B = (j < 50) ? bfr[j]
                                         : ldsB[(w * 14 + (j - 50)) * 64 + lane];
                    C[nt] = __builtin_amdgcn_mfma_f32_16x16x32_f16(
                                A, B, C[nt], 0, 0, 0);
                }
            }
            fcur = fnext;
        }

        // epilogue: lane L owns n = 64w + L; all C rows equal (broadcast A)
        const int g4 = lane >> 4;
        float m = (g4 == 0) ? C[0][0]
                : (g4 == 1) ? C[1][0]
                : (g4 == 2) ? C[2][0]
                :             C[3][0];
        float v = fmaxf(m + pv, 0.f);
        orow[w * 64 + lane] = v;              // drains lazily
        hbuf[nxt][w * 64 + lane] = (_Float16)v;
        __hip_atomic_store(&flags[w], t + 1, __ATOMIC_RELEASE,
                           __HIP_MEMORY_SCOPE_WORKGROUP);  // publish h(t+1)
    }
}

// ---------------- Fallback (no workspace): row-major W_h, one row per thread ----
__global__ __launch_bounds__(512)
void rnn_scan_row(const float* __restrict__ Wh,
                  const float* __restrict__ h0,
                  float* __restrict__ out)
{
    __shared__ float h[DLAT];
    const int b = blockIdx.x;
    const int r = threadIdx.x;
    h[r] = h0[(size_t)b * DLAT + r];
    __syncthreads();
    const float* wrow = Wh + (size_t)r * DLAT;
    for (int t = 0; t < TSTEPS; ++t) {
        float* orow = out + ((size_t)t * BATCH + b) * DLAT;
        float acc = orow[r];
        #pragma unroll 8
        for (int k = 0; k < DLAT; k += 4) {
            float4 w  = *(const float4*)(wrow + k);
            float4 hv = *(const float4*)&h[k];
            acc += w.x*hv.x + w.y*hv.y + w.z*hv.z + w.w*hv.w;
        }
        float v = fmaxf(acc, 0.f);
        __syncthreads();
        h[r] = v;
        orow[r] = v;
        __syncthreads();
    }
}

extern "C" void kernel_launch(void* const* d_in, const int* in_sizes, int n_in,
                              void* d_out, int out_size, void* d_ws, size_t ws_size,
                              hipStream_t stream)
{
    const float* x    = (const float*)d_in[0];
    const float* h0   = (const float*)d_in[1];
    const float* Win  = (const float*)d_in[2];
    const float* Wh   = (const float*)d_in[3];
    const float* bh   = (const float*)d_in[4];
    float* out = (float*)d_out;

    if (ws_size >= WS_TIER1) {
        _Float16* Wm = (_Float16*)d_ws;
        _Float16* Wf = (_Float16*)((char*)d_ws + WS_WF_OFF);
        pack_wh_mfma<<<128, 256, 0, stream>>>(Wh, Wm);
        pack_win_f16<<<64, 256, 0, stream>>>(Win, Wf);
        precompute_mfma<<<1024, 256, 0, stream>>>(x, (const half8_t*)Wf, bh, out);
        rnn_scan_mfma_pc<<<BATCH, 512, 0, stream>>>((const half8_t*)Wm, h0, out);
    } else if (ws_size >= WS_TIER2) {
        _Float16* Wm = (_Float16*)d_ws;
        dim3 gA(DLAT / BN, (TSTEPS * BATCH) / BM);   // (8, 512)
        pack_wh_mfma<<<128, 256, 0, stream>>>(Wh, Wm);
        precompute_gemm<<<gA, 256, 0, stream>>>(x, Win, bh, out);
        rnn_scan_mfma_pc<<<BATCH, 512, 0, stream>>>((const half8_t*)Wm, h0, out);
    } else {
        dim3 gA(DLAT / BN, (TSTEPS * BATCH) / BM);
        precompute_gemm<<<gA, 256, 0, stream>>>(x, Win, bh, out);
        rnn_scan_row<<<BATCH, 512, 0, stream>>>(Wh, h0, out);
    }
}

// Round 13
// 705.105 us; speedup vs baseline: 1.1444x; 1.1444x over previous
//
#include <hip/hip_runtime.h>

#define TSTEPS 512
#define BATCH  64
#define DIN    256
#define DLAT   512

typedef _Float16 half8_t __attribute__((ext_vector_type(8)));
typedef float    f32x4  __attribute__((ext_vector_type(4)));

// d_ws layout: [0, 512K) = Wm (scan W_h frags); [512K, 768K) = Wf (W_in frags)
#define WS_WF_OFF  (512u * 1024u)
#define WS_TIER2   (512u * 1024u)
#define WS_TIER1   (768u * 1024u)

// Barrier waiting only on LDS ops (lgkmcnt), not outstanding global stores.
__device__ __forceinline__ void barrier_lds_only()
{
    __builtin_amdgcn_sched_barrier(0);
    asm volatile("s_waitcnt lgkmcnt(0)\n\ts_barrier" ::: "memory");
    __builtin_amdgcn_sched_barrier(0);
}

// ---------------- Kernel A (tier2 fallback): fp32 tiled GEMM --------------------
#define BM 64
#define BN 64
#define BK 32

__global__ __launch_bounds__(256)
void precompute_gemm(const float* __restrict__ x,
                     const float* __restrict__ Win,
                     const float* __restrict__ bh,
                     float* __restrict__ P)
{
    __shared__ float As[BM][BK + 1];
    __shared__ float Ws[BN][BK + 1];
    const int m0  = blockIdx.y * BM;
    const int n0  = blockIdx.x * BN;
    const int tid = threadIdx.x;
    const int tx  = tid & 15;
    const int ty  = tid >> 4;
    const int lr  = tid >> 2;
    const int lc  = (tid & 3) * 8;

    float acc[4][4] = {};

    for (int kk = 0; kk < DIN; kk += BK) {
        const float* ax = x   + (size_t)(m0 + lr) * DIN + kk + lc;
        const float* aw = Win + (size_t)(n0 + lr) * DIN + kk + lc;
        float4 a0 = *(const float4*)(ax);
        float4 a1 = *(const float4*)(ax + 4);
        float4 w0 = *(const float4*)(aw);
        float4 w1 = *(const float4*)(aw + 4);
        As[lr][lc+0]=a0.x; As[lr][lc+1]=a0.y; As[lr][lc+2]=a0.z; As[lr][lc+3]=a0.w;
        As[lr][lc+4]=a1.x; As[lr][lc+5]=a1.y; As[lr][lc+6]=a1.z; As[lr][lc+7]=a1.w;
        Ws[lr][lc+0]=w0.x; Ws[lr][lc+1]=w0.y; Ws[lr][lc+2]=w0.z; Ws[lr][lc+3]=w0.w;
        Ws[lr][lc+4]=w1.x; Ws[lr][lc+5]=w1.y; Ws[lr][lc+6]=w1.z; Ws[lr][lc+7]=w1.w;
        __syncthreads();
        #pragma unroll
        for (int k = 0; k < BK; ++k) {
            float a[4], w[4];
            #pragma unroll
            for (int i = 0; i < 4; ++i) a[i] = As[ty*4+i][k];
            #pragma unroll
            for (int j = 0; j < 4; ++j) w[j] = Ws[tx*4+j][k];
            #pragma unroll
            for (int i = 0; i < 4; ++i)
                #pragma unroll
                for (int j = 0; j < 4; ++j)
                    acc[i][j] += a[i] * w[j];
        }
        __syncthreads();
    }

    float4 bv = *(const float4*)(bh + n0 + tx*4);
    #pragma unroll
    for (int i = 0; i < 4; ++i) {
        float4 v;
        v.x = acc[i][0] + bv.x; v.y = acc[i][1] + bv.y;
        v.z = acc[i][2] + bv.z; v.w = acc[i][3] + bv.w;
        *(float4*)(P + (size_t)(m0 + ty*4 + i) * DLAT + n0 + tx*4) = v;
    }
}

// -------- Pack W_h into MFMA B-fragment order (fp16) ----------------------------
// Tile (kt, ntg): 32 k x 16 n; element (lane, e) = W_h[ntg*16+(lane&15)]
// [kt*32+(lane>>4)*8+e]. Flat: Wm[(tile*64+lane)*8+e], tile = kt*32+ntg.
// Verified on HW R8-R12 (absmax 0.03125).
__global__ __launch_bounds__(256)
void pack_wh_mfma(const float* __restrict__ Wh, _Float16* __restrict__ Wm)
{
    const int idx  = blockIdx.x * 256 + threadIdx.x;  // 32768 = 512 tiles x 64
    const int lane = idx & 63;
    const int tile = idx >> 6;
    const int kt   = tile >> 5;
    const int ntg  = tile & 31;
    const int n    = ntg * 16 + (lane & 15);
    const int k0   = kt * 32 + (lane >> 4) * 8;
    half8_t v;
    #pragma unroll
    for (int e = 0; e < 8; ++e)
        v[e] = (_Float16)Wh[(size_t)n * DLAT + k0 + e];
    *(half8_t*)(Wm + (size_t)idx * 8) = v;
}

// -------- Pack W_in into MFMA B-fragment order (fp16), K = DIN = 256 ------------
__global__ __launch_bounds__(256)
void pack_win_f16(const float* __restrict__ Win, _Float16* __restrict__ Wf)
{
    const int idx  = blockIdx.x * 256 + threadIdx.x;  // 16384 = 256 tiles x 64
    const int lane = idx & 63;
    const int tile = idx >> 6;
    const int kt   = tile >> 5;
    const int ntg  = tile & 31;
    const int n    = ntg * 16 + (lane & 15);
    const int k0   = kt * 32 + (lane >> 4) * 8;
    half8_t v;
    #pragma unroll
    for (int e = 0; e < 8; ++e)
        v[e] = (_Float16)Win[(size_t)n * DIN + k0 + e];
    *(half8_t*)(Wf + (size_t)idx * 8) = v;
}

// ---------------- Kernel A (tier1): f16 MFMA GEMM  P = x @ Win^T + bh -----------
__global__ __launch_bounds__(256)
void precompute_mfma(const float* __restrict__ x,
                     const half8_t* __restrict__ Wf,
                     const float* __restrict__ bh,
                     float* __restrict__ P)
{
    const int tid  = threadIdx.x;
    const int wave = tid >> 6, lane = tid & 63;
    const int wm   = wave >> 1, wn = wave & 1;
    const int m0   = (blockIdx.x >> 2) * 128 + wm * 64;
    const int n0   = (blockIdx.x & 3) * 128 + wn * 64;
    const int col  = lane & 15, rg = lane >> 4;

    float bv[4];
    #pragma unroll
    for (int nt = 0; nt < 4; ++nt) bv[nt] = bh[n0 + nt * 16 + col];

    f32x4 C[4][4] = {};

    #pragma unroll
    for (int kt = 0; kt < 8; ++kt) {
        half8_t A[4];
        #pragma unroll
        for (int mt = 0; mt < 4; ++mt) {
            const float* xp = x + (size_t)(m0 + mt * 16 + col) * DIN
                                + kt * 32 + rg * 8;
            float4 a = *(const float4*)xp;
            float4 b = *(const float4*)(xp + 4);
            half8_t v;
            v[0] = (_Float16)a.x; v[1] = (_Float16)a.y;
            v[2] = (_Float16)a.z; v[3] = (_Float16)a.w;
            v[4] = (_Float16)b.x; v[5] = (_Float16)b.y;
            v[6] = (_Float16)b.z; v[7] = (_Float16)b.w;
            A[mt] = v;
        }
        half8_t B[4];
        #pragma unroll
        for (int nt = 0; nt < 4; ++nt)
            B[nt] = Wf[(size_t)((kt * 32 + (n0 >> 4) + nt) * 64) + lane];
        #pragma unroll
        for (int mt = 0; mt < 4; ++mt)
            #pragma unroll
            for (int nt = 0; nt < 4; ++nt)
                C[mt][nt] = __builtin_amdgcn_mfma_f32_16x16x32_f16(
                                A[mt], B[nt], C[mt][nt], 0, 0, 0);
    }

    #pragma unroll
    for (int mt = 0; mt < 4; ++mt)
        #pragma unroll
        for (int nt = 0; nt < 4; ++nt) {
            #pragma unroll
            for (int r = 0; r < 4; ++r) {
                const int m = m0 + mt * 16 + rg * 4 + r;
                P[(size_t)m * DLAT + n0 + nt * 16 + col] = C[mt][nt][r] + bv[nt];
            }
        }
}

// ---------------- Kernel B: MFMA scan, staggered kt + 2-deep A prefetch ---------
// One chain per WG; 512 threads = 8 waves, 2/SIMD. Wave w owns n [64w,64w+64):
// 4 nt x 16 kt = 64 MFMA/step. NEW vs R11:
//  (1) per-wave kt-stagger (kt0 = 2w): SIMD partners start 8 kt apart, so
//      their ds_read bursts and MFMA chains interleave instead of colliding
//      in barrier-lockstep (the suspected ~1280 cyc/step correlated stall);
//  (2) explicit 2-deep A-frag prefetch (chunks of 2 kt, static indices) hides
//      the ~120 cyc LDS latency under >=8 MFMAs;
//  (3) s_setprio(1) around the MFMA block.
// B-frags: j = s*4+nt (s = stagger-order segment): j<48 in registers (32 AGPR
// frags read natively by MFMA + 16 arch), j>=48 in LDS (16 frags x 8 waves =
// 128 KB, [slot][lane] b128 conflict-free). Epilogue: lane L owns n = 64w+L;
// all C rows equal (broadcast A). Summation order per output is a fixed kt
// rotation - deterministic, R12-verified absmax-safe.
__global__ __launch_bounds__(512, 2)
void rnn_scan_stag(const half8_t* __restrict__ Wm,   // fragment-packed
                   const float* __restrict__ h0,
                   float* __restrict__ out)          // P in, h_seq out (in place)
{
    __shared__ half8_t  ldsB[8 * 16 * 64];   // 128 KB: [(w*16 + slot)*64 + lane]
    __shared__ _Float16 hbuf[2][DLAT];       // 2 KB, double-buffered h

    const int b    = blockIdx.x;
    const int tid  = threadIdx.x;
    const int w    = tid >> 6;               // wave 0..7: n-range 64w
    const int lane = tid & 63;
    const int kt0  = 2 * w;                  // stagger origin

    // ---- one-time: B frags in stagger order; j = s*4+nt static ----
    half8_t bfr[48];
    #pragma unroll
    for (int s = 0; s < 16; ++s) {
        const int kt = (kt0 + s) & 15;
        #pragma unroll
        for (int nt = 0; nt < 4; ++nt) {
            const int j = s * 4 + nt;
            half8_t v = Wm[(size_t)((kt * 32 + w * 4 + nt) * 64) + lane];
            if (j < 48) bfr[j] = v;
            else        ldsB[(w * 16 + (j - 48)) * 64 + lane] = v;
        }
    }

    hbuf[0][tid] = (_Float16)h0[(size_t)b * DLAT + tid];   // pre-relu h0
    __syncthreads();

    for (int t = 0; t < TSTEPS; ++t) {
        const int cur = t & 1, nxt = cur ^ 1;
        float* orow = out + ((size_t)t * BATCH + b) * DLAT;
        float pv = orow[w * 64 + lane];      // prefetch P (hidden under MFMAs)

        f32x4 C[4] = {};
        half8_t Ap[2][2];                    // 2-deep chunk prefetch (static idx)
        #pragma unroll
        for (int i = 0; i < 4; ++i) {        // prime chunks 0,1 (segments 0..3)
            const int kt = (kt0 + i) & 15;
            Ap[i >> 1][i & 1] =
                *(const half8_t*)&hbuf[cur][kt * 32 + (lane >> 4) * 8];
        }
        __builtin_amdgcn_s_setprio(1);
        #pragma unroll
        for (int c = 0; c < 8; ++c) {        // 8 chunks x 2 segments
            const int pb = c & 1;
            #pragma unroll
            for (int i = 0; i < 2; ++i) {
                const int s = c * 2 + i;
                half8_t Av = Ap[pb][i];
                #pragma unroll
                for (int nt = 0; nt < 4; ++nt) {
                    const int j = s * 4 + nt;
                    half8_t B = (j < 48) ? bfr[j]
                                         : ldsB[(w * 16 + (j - 48)) * 64 + lane];
                    C[nt] = __builtin_amdgcn_mfma_f32_16x16x32_f16(
                                Av, B, C[nt], 0, 0, 0);
                }
            }
            if (c < 6) {                     // refill this buffer 2 chunks ahead
                #pragma unroll
                for (int i = 0; i < 2; ++i) {
                    const int s = (c + 2) * 2 + i;
                    const int kt = (kt0 + s) & 15;
                    Ap[pb][i] =
                        *(const half8_t*)&hbuf[cur][kt * 32 + (lane >> 4) * 8];
                }
            }
        }
        __builtin_amdgcn_s_setprio(0);

        // epilogue: all 64 lanes; lane L -> nt = L>>4, col = L&15, n = 64w + L
        const int g4 = lane >> 4;
        float m = (g4 == 0) ? C[0][0]
                : (g4 == 1) ? C[1][0]
                : (g4 == 2) ? C[2][0]
                :             C[3][0];       // all C rows equal (broadcast A)
        float v = fmaxf(m + pv, 0.f);
        orow[w * 64 + lane] = v;             // HBM store: drains lazily
        hbuf[nxt][w * 64 + lane] = (_Float16)v;
        barrier_lds_only();                  // wait LDS only; not the HBM store
    }
}

// ---------------- Fallback (no workspace): row-major W_h, one row per thread ----
__global__ __launch_bounds__(512)
void rnn_scan_row(const float* __restrict__ Wh,
                  const float* __restrict__ h0,
                  float* __restrict__ out)
{
    __shared__ float h[DLAT];
    const int b = blockIdx.x;
    const int r = threadIdx.x;
    h[r] = h0[(size_t)b * DLAT + r];
    __syncthreads();
    const float* wrow = Wh + (size_t)r * DLAT;
    for (int t = 0; t < TSTEPS; ++t) {
        float* orow = out + ((size_t)t * BATCH + b) * DLAT;
        float acc = orow[r];
        #pragma unroll 8
        for (int k = 0; k < DLAT; k += 4) {
            float4 w  = *(const float4*)(wrow + k);
            float4 hv = *(const float4*)&h[k];
            acc += w.x*hv.x + w.y*hv.y + w.z*hv.z + w.w*hv.w;
        }
        float v = fmaxf(acc, 0.f);
        __syncthreads();
        h[r] = v;
        orow[r] = v;
        __syncthreads();
    }
}

extern "C" void kernel_launch(void* const* d_in, const int* in_sizes, int n_in,
                              void* d_out, int out_size, void* d_ws, size_t ws_size,
                              hipStream_t stream)
{
    const float* x    = (const float*)d_in[0];
    const float* h0   = (const float*)d_in[1];
    const float* Win  = (const float*)d_in[2];
    const float* Wh   = (const float*)d_in[3];
    const float* bh   = (const float*)d_in[4];
    float* out = (float*)d_out;

    if (ws_size >= WS_TIER1) {
        _Float16* Wm = (_Float16*)d_ws;
        _Float16* Wf = (_Float16*)((char*)d_ws + WS_WF_OFF);
        pack_wh_mfma<<<128, 256, 0, stream>>>(Wh, Wm);
        pack_win_f16<<<64, 256, 0, stream>>>(Win, Wf);
        precompute_mfma<<<1024, 256, 0, stream>>>(x, (const half8_t*)Wf, bh, out);
        rnn_scan_stag<<<BATCH, 512, 0, stream>>>((const half8_t*)Wm, h0, out);
    } else if (ws_size >= WS_TIER2) {
        _Float16* Wm = (_Float16*)d_ws;
        dim3 gA(DLAT / BN, (TSTEPS * BATCH) / BM);   // (8, 512)
        pack_wh_mfma<<<128, 256, 0, stream>>>(Wh, Wm);
        precompute_gemm<<<gA, 256, 0, stream>>>(x, Win, bh, out);
        rnn_scan_stag<<<BATCH, 512, 0, stream>>>((const half8_t*)Wm, h0, out);
    } else {
        dim3 gA(DLAT / BN, (TSTEPS * BATCH) / BM);
        precompute_gemm<<<gA, 256, 0, stream>>>(x, Win, bh, out);
        rnn_scan_row<<<BATCH, 512, 0, stream>>>(Wh, h0, out);
    }
}

// Round 14
// 676.208 us; speedup vs baseline: 1.1934x; 1.0427x over previous
//
#include <hip/hip_runtime.h>

#define TSTEPS 512
#define BATCH  64
#define DIN    256
#define DLAT   512

typedef _Float16 half8_t __attribute__((ext_vector_type(8)));
typedef float    f32x4  __attribute__((ext_vector_type(4)));

// d_ws layout: [0, 512K) = Wm (scan W_h frags); [512K, 768K) = Wf (W_in frags)
#define WS_WF_OFF  (512u * 1024u)
#define WS_TIER2   (512u * 1024u)
#define WS_TIER1   (768u * 1024u)

// Barrier waiting only on LDS ops (lgkmcnt), not outstanding global stores.
__device__ __forceinline__ void barrier_lds_only()
{
    __builtin_amdgcn_sched_barrier(0);
    asm volatile("s_waitcnt lgkmcnt(0)\n\ts_barrier" ::: "memory");
    __builtin_amdgcn_sched_barrier(0);
}

// ---------------- Kernel A (tier2 fallback): fp32 tiled GEMM --------------------
#define BM 64
#define BN 64
#define BK 32

__global__ __launch_bounds__(256)
void precompute_gemm(const float* __restrict__ x,
                     const float* __restrict__ Win,
                     const float* __restrict__ bh,
                     float* __restrict__ P)
{
    __shared__ float As[BM][BK + 1];
    __shared__ float Ws[BN][BK + 1];
    const int m0  = blockIdx.y * BM;
    const int n0  = blockIdx.x * BN;
    const int tid = threadIdx.x;
    const int tx  = tid & 15;
    const int ty  = tid >> 4;
    const int lr  = tid >> 2;
    const int lc  = (tid & 3) * 8;

    float acc[4][4] = {};

    for (int kk = 0; kk < DIN; kk += BK) {
        const float* ax = x   + (size_t)(m0 + lr) * DIN + kk + lc;
        const float* aw = Win + (size_t)(n0 + lr) * DIN + kk + lc;
        float4 a0 = *(const float4*)(ax);
        float4 a1 = *(const float4*)(ax + 4);
        float4 w0 = *(const float4*)(aw);
        float4 w1 = *(const float4*)(aw + 4);
        As[lr][lc+0]=a0.x; As[lr][lc+1]=a0.y; As[lr][lc+2]=a0.z; As[lr][lc+3]=a0.w;
        As[lr][lc+4]=a1.x; As[lr][lc+5]=a1.y; As[lr][lc+6]=a1.z; As[lr][lc+7]=a1.w;
        Ws[lr][lc+0]=w0.x; Ws[lr][lc+1]=w0.y; Ws[lr][lc+2]=w0.z; Ws[lr][lc+3]=w0.w;
        Ws[lr][lc+4]=w1.x; Ws[lr][lc+5]=w1.y; Ws[lr][lc+6]=w1.z; Ws[lr][lc+7]=w1.w;
        __syncthreads();
        #pragma unroll
        for (int k = 0; k < BK; ++k) {
            float a[4], w[4];
            #pragma unroll
            for (int i = 0; i < 4; ++i) a[i] = As[ty*4+i][k];
            #pragma unroll
            for (int j = 0; j < 4; ++j) w[j] = Ws[tx*4+j][k];
            #pragma unroll
            for (int i = 0; i < 4; ++i)
                #pragma unroll
                for (int j = 0; j < 4; ++j)
                    acc[i][j] += a[i] * w[j];
        }
        __syncthreads();
    }

    float4 bv = *(const float4*)(bh + n0 + tx*4);
    #pragma unroll
    for (int i = 0; i < 4; ++i) {
        float4 v;
        v.x = acc[i][0] + bv.x; v.y = acc[i][1] + bv.y;
        v.z = acc[i][2] + bv.z; v.w = acc[i][3] + bv.w;
        *(float4*)(P + (size_t)(m0 + ty*4 + i) * DLAT + n0 + tx*4) = v;
    }
}

// -------- Pack W_h into MFMA B-fragment order (fp16) ----------------------------
// Tile (kt, ntg): 32 k x 16 n; element (lane, e) = W_h[ntg*16+(lane&15)]
// [kt*32+(lane>>4)*8+e]. Flat: Wm[(tile*64+lane)*8+e], tile = kt*32+ntg.
// Verified on HW R8-R13 (absmax 0.03125).
__global__ __launch_bounds__(256)
void pack_wh_mfma(const float* __restrict__ Wh, _Float16* __restrict__ Wm)
{
    const int idx  = blockIdx.x * 256 + threadIdx.x;  // 32768 = 512 tiles x 64
    const int lane = idx & 63;
    const int tile = idx >> 6;
    const int kt   = tile >> 5;
    const int ntg  = tile & 31;
    const int n    = ntg * 16 + (lane & 15);
    const int k0   = kt * 32 + (lane >> 4) * 8;
    half8_t v;
    #pragma unroll
    for (int e = 0; e < 8; ++e)
        v[e] = (_Float16)Wh[(size_t)n * DLAT + k0 + e];
    *(half8_t*)(Wm + (size_t)idx * 8) = v;
}

// -------- Pack W_in into MFMA B-fragment order (fp16), K = DIN = 256 ------------
__global__ __launch_bounds__(256)
void pack_win_f16(const float* __restrict__ Win, _Float16* __restrict__ Wf)
{
    const int idx  = blockIdx.x * 256 + threadIdx.x;  // 16384 = 256 tiles x 64
    const int lane = idx & 63;
    const int tile = idx >> 6;
    const int kt   = tile >> 5;
    const int ntg  = tile & 31;
    const int n    = ntg * 16 + (lane & 15);
    const int k0   = kt * 32 + (lane >> 4) * 8;
    half8_t v;
    #pragma unroll
    for (int e = 0; e < 8; ++e)
        v[e] = (_Float16)Win[(size_t)n * DIN + k0 + e];
    *(half8_t*)(Wf + (size_t)idx * 8) = v;
}

// ---------------- Kernel A (tier1): f16 MFMA GEMM  P = x @ Win^T + bh -----------
__global__ __launch_bounds__(256)
void precompute_mfma(const float* __restrict__ x,
                     const half8_t* __restrict__ Wf,
                     const float* __restrict__ bh,
                     float* __restrict__ P)
{
    const int tid  = threadIdx.x;
    const int wave = tid >> 6, lane = tid & 63;
    const int wm   = wave >> 1, wn = wave & 1;
    const int m0   = (blockIdx.x >> 2) * 128 + wm * 64;
    const int n0   = (blockIdx.x & 3) * 128 + wn * 64;
    const int col  = lane & 15, rg = lane >> 4;

    float bv[4];
    #pragma unroll
    for (int nt = 0; nt < 4; ++nt) bv[nt] = bh[n0 + nt * 16 + col];

    f32x4 C[4][4] = {};

    #pragma unroll
    for (int kt = 0; kt < 8; ++kt) {
        half8_t A[4];
        #pragma unroll
        for (int mt = 0; mt < 4; ++mt) {
            const float* xp = x + (size_t)(m0 + mt * 16 + col) * DIN
                                + kt * 32 + rg * 8;
            float4 a = *(const float4*)xp;
            float4 b = *(const float4*)(xp + 4);
            half8_t v;
            v[0] = (_Float16)a.x; v[1] = (_Float16)a.y;
            v[2] = (_Float16)a.z; v[3] = (_Float16)a.w;
            v[4] = (_Float16)b.x; v[5] = (_Float16)b.y;
            v[6] = (_Float16)b.z; v[7] = (_Float16)b.w;
            A[mt] = v;
        }
        half8_t B[4];
        #pragma unroll
        for (int nt = 0; nt < 4; ++nt)
            B[nt] = Wf[(size_t)((kt * 32 + (n0 >> 4) + nt) * 64) + lane];
        #pragma unroll
        for (int mt = 0; mt < 4; ++mt)
            #pragma unroll
            for (int nt = 0; nt < 4; ++nt)
                C[mt][nt] = __builtin_amdgcn_mfma_f32_16x16x32_f16(
                                A[mt], B[nt], C[mt][nt], 0, 0, 0);
    }

    #pragma unroll
    for (int mt = 0; mt < 4; ++mt)
        #pragma unroll
        for (int nt = 0; nt < 4; ++nt) {
            #pragma unroll
            for (int r = 0; r < 4; ++r) {
                const int m = m0 + mt * 16 + rg * 4 + r;
                P[(size_t)m * DLAT + n0 + nt * 16 + col] = C[mt][nt][r] + bv[nt];
            }
        }
}

// ---------------- Kernel B: scan, spread+prefetched B-LDS, pre-barrier prime ----
// R13 structure (8 waves, stagger kt0=2w, 2-deep A prefetch, setprio, lds-only
// barrier) plus:
//  (1) B-LDS frags spread 2-per-chunk (odd segment, nt 2,3) and prefetched one
//      chunk ahead into Bp[2] - removes the end-of-loop LDS latency burst;
//  (2) pre-barrier priming: chunk 0 of the next step is the wave's OWN kt
//      slice (kt0=2w covers k [64w,64w+64) = what its epilogue just wrote), so
//      Ap[0] + Bp (step-invariant) load BEFORE the barrier; only Ap[1] (other
//      waves' h) waits. Removes the post-barrier serial LDS window.
// B-frags: even s: bfr[c*6+nt]; odd s: nt 0,1 -> bfr[c*6+4+nt], nt 2,3 -> LDS
// slot c*2+(nt-2). 48 reg-frags + 16 LDS x 8 waves = 128 KB.
__global__ __launch_bounds__(512, 2)
void rnn_scan_pf(const half8_t* __restrict__ Wm,   // fragment-packed
                 const float* __restrict__ h0,
                 float* __restrict__ out)          // P in, h_seq out (in place)
{
    __shared__ half8_t  ldsB[8 * 16 * 64];   // 128 KB: [(w*16 + slot)*64 + lane]
    __shared__ _Float16 hbuf[2][DLAT];       // 2 KB, double-buffered h

    const int b    = blockIdx.x;
    const int tid  = threadIdx.x;
    const int w    = tid >> 6;               // wave 0..7: n-range 64w
    const int lane = tid & 63;
    const int kt0  = 2 * w;                  // stagger origin
    const int aoff = (lane >> 4) * 8;        // A-frag k sub-offset

    // ---- one-time: B frags; LDS frags = odd s, nt>=2 (2 per chunk) ----
    half8_t bfr[48];
    #pragma unroll
    for (int s = 0; s < 16; ++s) {
        const int c  = s >> 1;
        const int kt = (kt0 + s) & 15;
        #pragma unroll
        for (int nt = 0; nt < 4; ++nt) {
            half8_t v = Wm[(size_t)((kt * 32 + w * 4 + nt) * 64) + lane];
            if ((s & 1) && nt >= 2) ldsB[(w * 16 + c * 2 + (nt - 2)) * 64 + lane] = v;
            else                    bfr[c * 6 + ((s & 1) ? 4 + nt : nt)] = v;
        }
    }

    hbuf[0][tid] = (_Float16)h0[(size_t)b * DLAT + tid];   // pre-relu h0
    __syncthreads();

    // ---- prime chunk 0,1 A-frags and chunk 0 B-LDS frags ----
    half8_t Ap[2][2], Bp[2];
    #pragma unroll
    for (int i = 0; i < 4; ++i)
        Ap[i >> 1][i & 1] =
            *(const half8_t*)&hbuf[0][((kt0 + i) & 15) * 32 + aoff];
    Bp[0] = ldsB[(w * 16 + 0) * 64 + lane];
    Bp[1] = ldsB[(w * 16 + 1) * 64 + lane];

    for (int t = 0; t < TSTEPS; ++t) {
        const int cur = t & 1, nxt = cur ^ 1;
        float* orow = out + ((size_t)t * BATCH + b) * DLAT;
        float pv = orow[w * 64 + lane];      // prefetch P (hidden under MFMAs)

        f32x4 C[4] = {};
        __builtin_amdgcn_s_setprio(1);
        #pragma unroll
        for (int c = 0; c < 8; ++c) {        // 8 chunks x 2 segments
            const int pb = c & 1;
            // segment s = 2c (even): all 4 B from registers
            #pragma unroll
            for (int nt = 0; nt < 4; ++nt)
                C[nt] = __builtin_amdgcn_mfma_f32_16x16x32_f16(
                            Ap[pb][0], bfr[c * 6 + nt], C[nt], 0, 0, 0);
            // segment s = 2c+1 (odd): nt 0,1 reg; nt 2,3 prefetched LDS
            C[0] = __builtin_amdgcn_mfma_f32_16x16x32_f16(
                        Ap[pb][1], bfr[c * 6 + 4], C[0], 0, 0, 0);
            C[1] = __builtin_amdgcn_mfma_f32_16x16x32_f16(
                        Ap[pb][1], bfr[c * 6 + 5], C[1], 0, 0, 0);
            C[2] = __builtin_amdgcn_mfma_f32_16x16x32_f16(
                        Ap[pb][1], Bp[0], C[2], 0, 0, 0);
            C[3] = __builtin_amdgcn_mfma_f32_16x16x32_f16(
                        Ap[pb][1], Bp[1], C[3], 0, 0, 0);
            // refills (static indices; compiler orders after uses)
            if (c < 7) {                     // next chunk's 2 LDS B-frags
                Bp[0] = ldsB[(w * 16 + (c + 1) * 2 + 0) * 64 + lane];
                Bp[1] = ldsB[(w * 16 + (c + 1) * 2 + 1) * 64 + lane];
            }
            if (c < 6) {                     // A-frags 2 chunks ahead
                #pragma unroll
                for (int i = 0; i < 2; ++i) {
                    const int s = (c + 2) * 2 + i;
                    Ap[pb][i] =
                        *(const half8_t*)&hbuf[cur][((kt0 + s) & 15) * 32 + aoff];
                }
            }
        }
        __builtin_amdgcn_s_setprio(0);

        // epilogue: lane L owns n = 64w + L; all C rows equal (broadcast A)
        const int g4 = lane >> 4;
        float m = (g4 == 0) ? C[0][0]
                : (g4 == 1) ? C[1][0]
                : (g4 == 2) ? C[2][0]
                :             C[3][0];
        float v = fmaxf(m + pv, 0.f);
        orow[w * 64 + lane] = v;             // HBM store: drains lazily
        hbuf[nxt][w * 64 + lane] = (_Float16)v;

        // pre-barrier prime for next step's chunk 0: OWN slice (just written,
        // same-wave DS ordering) + step-invariant B slots.
        Ap[0][0] = *(const half8_t*)&hbuf[nxt][((kt0 + 0) & 15) * 32 + aoff];
        Ap[0][1] = *(const half8_t*)&hbuf[nxt][((kt0 + 1) & 15) * 32 + aoff];
        Bp[0] = ldsB[(w * 16 + 0) * 64 + lane];
        Bp[1] = ldsB[(w * 16 + 1) * 64 + lane];

        barrier_lds_only();                  // wait LDS only; not the HBM store

        // post-barrier: chunk 1 A-frags (other waves' h, now published)
        Ap[1][0] = *(const half8_t*)&hbuf[nxt][((kt0 + 2) & 15) * 32 + aoff];
        Ap[1][1] = *(const half8_t*)&hbuf[nxt][((kt0 + 3) & 15) * 32 + aoff];
    }
}

// ---------------- Fallback (no workspace): row-major W_h, one row per thread ----
__global__ __launch_bounds__(512)
void rnn_scan_row(const float* __restrict__ Wh,
                  const float* __restrict__ h0,
                  float* __restrict__ out)
{
    __shared__ float h[DLAT];
    const int b = blockIdx.x;
    const int r = threadIdx.x;
    h[r] = h0[(size_t)b * DLAT + r];
    __syncthreads();
    const float* wrow = Wh + (size_t)r * DLAT;
    for (int t = 0; t < TSTEPS; ++t) {
        float* orow = out + ((size_t)t * BATCH + b) * DLAT;
        float acc = orow[r];
        #pragma unroll 8
        for (int k = 0; k < DLAT; k += 4) {
            float4 w  = *(const float4*)(wrow + k);
            float4 hv = *(const float4*)&h[k];
            acc += w.x*hv.x + w.y*hv.y + w.z*hv.z + w.w*hv.w;
        }
        float v = fmaxf(acc, 0.f);
        __syncthreads();
        h[r] = v;
        orow[r] = v;
        __syncthreads();
    }
}

extern "C" void kernel_launch(void* const* d_in, const int* in_sizes, int n_in,
                              void* d_out, int out_size, void* d_ws, size_t ws_size,
                              hipStream_t stream)
{
    const float* x    = (const float*)d_in[0];
    const float* h0   = (const float*)d_in[1];
    const float* Win  = (const float*)d_in[2];
    const float* Wh   = (const float*)d_in[3];
    const float* bh   = (const float*)d_in[4];
    float* out = (float*)d_out;

    if (ws_size >= WS_TIER1) {
        _Float16* Wm = (_Float16*)d_ws;
        _Float16* Wf = (_Float16*)((char*)d_ws + WS_WF_OFF);
        pack_wh_mfma<<<128, 256, 0, stream>>>(Wh, Wm);
        pack_win_f16<<<64, 256, 0, stream>>>(Win, Wf);
        precompute_mfma<<<1024, 256, 0, stream>>>(x, (const half8_t*)Wf, bh, out);
        rnn_scan_pf<<<BATCH, 512, 0, stream>>>((const half8_t*)Wm, h0, out);
    } else if (ws_size >= WS_TIER2) {
        _Float16* Wm = (_Float16*)d_ws;
        dim3 gA(DLAT / BN, (TSTEPS * BATCH) / BM);   // (8, 512)
        pack_wh_mfma<<<128, 256, 0, stream>>>(Wh, Wm);
        precompute_gemm<<<gA, 256, 0, stream>>>(x, Win, bh, out);
        rnn_scan_pf<<<BATCH, 512, 0, stream>>>((const half8_t*)Wm, h0, out);
    } else {
        dim3 gA(DLAT / BN, (TSTEPS * BATCH) / BM);
        precompute_gemm<<<gA, 256, 0, stream>>>(x, Win, bh, out);
        rnn_scan_row<<<BATCH, 512, 0, stream>>>(Wh, h0, out);
    }
}